// Round 1
// baseline (111.707 us; speedup 1.0000x reference)
//
#include <hip/hip_runtime.h>
#include <hip/hip_bf16.h>
#include <math.h>

#define B 16
#define V 100000
#define S 4096
#define BS (B * S)   // 65536

// ---------------------------------------------------------------------------
// Kernel 1: gather sampled points + precompute squared norm.
// Writes float4(x, y, z, x^2+y^2+z^2) per sampled point, SoA over [set][b*S+i].
// ---------------------------------------------------------------------------
__global__ __launch_bounds__(256) void chamfer_gather_kernel(
    const float* __restrict__ src_verts, const float* __restrict__ dst_verts,
    const int* __restrict__ src_idx, const int* __restrict__ dst_idx,
    float4* __restrict__ srcp, float4* __restrict__ dstp) {
  int t = blockIdx.x * 256 + threadIdx.x;
  if (t >= 2 * BS) return;
  int set = t >> 16;          // 0 = src, 1 = dst
  int i = t & (BS - 1);       // 0 .. B*S-1
  const float* verts = set ? dst_verts : src_verts;
  const int* idx = set ? dst_idx : src_idx;
  float4* op = set ? dstp : srcp;
  int b = i >> 12;            // i / S
  int v = idx[i];
  v = v < 0 ? 0 : (v >= V ? V - 1 : v);  // defensive clamp (no OOB faults)
  const float* p = verts + ((size_t)b * V + (size_t)v) * 3;
  float x = p[0], y = p[1], z = p[2];
  op[i] = make_float4(x, y, z, x * x + y * y + z * z);
}

// ---------------------------------------------------------------------------
// Kernel 2: per (batch, direction, chunk-of-512-queries) block.
//   dir 0: queries = src points, others = dst points  (min over dst)
//   dir 1: queries = dst points, others = src points  (min over src)
// Stages all 4096 "other" points (float4 = 64 KB) in LDS; each thread owns
// 2 queries and computes min_j (d2_j - 2*dot) over all points; then
// val = max(s2_q + min, 0). Block sums -> one atomicAdd per wave.
// Grid = B * 2 * 8 = 256 blocks (1 per CU).
// ---------------------------------------------------------------------------
__global__ __launch_bounds__(256) void chamfer_min_kernel(
    const float4* __restrict__ srcp, const float4* __restrict__ dstp,
    float* __restrict__ out) {
  __shared__ float4 pts[S];  // 64 KB

  int bid = blockIdx.x;
  int b = bid >> 4;          // /16
  int rem = bid & 15;
  int dir = rem >> 3;
  int chunk = rem & 7;

  const float4* qbase = dir == 0 ? srcp : dstp;
  const float4* obase = dir == 0 ? dstp : srcp;
  const float4* op = obase + (size_t)b * S;

  int tid = threadIdx.x;
  // cooperative, coalesced LDS fill: 4096 float4 / 256 threads = 16 each
  #pragma unroll
  for (int i = 0; i < S / 256; ++i) {
    pts[i * 256 + tid] = op[i * 256 + tid];
  }
  __syncthreads();

  int qoff = b * S + chunk * 512 + tid;
  float4 q0 = qbase[qoff];
  float4 q1 = qbase[qoff + 256];

  float m0 = INFINITY;
  float m1 = INFINITY;

  #pragma unroll 4
  for (int j = 0; j < S; j += 4) {
    float4 p0 = pts[j + 0];
    float4 p1 = pts[j + 1];
    float4 p2 = pts[j + 2];
    float4 p3 = pts[j + 3];

    float a0 = fmaf(-2.f, fmaf(q0.x, p0.x, fmaf(q0.y, p0.y, q0.z * p0.z)), p0.w);
    float a1 = fmaf(-2.f, fmaf(q0.x, p1.x, fmaf(q0.y, p1.y, q0.z * p1.z)), p1.w);
    float a2 = fmaf(-2.f, fmaf(q0.x, p2.x, fmaf(q0.y, p2.y, q0.z * p2.z)), p2.w);
    float a3 = fmaf(-2.f, fmaf(q0.x, p3.x, fmaf(q0.y, p3.y, q0.z * p3.z)), p3.w);
    m0 = fminf(m0, fminf(fminf(a0, a1), fminf(a2, a3)));

    float b0 = fmaf(-2.f, fmaf(q1.x, p0.x, fmaf(q1.y, p0.y, q1.z * p0.z)), p0.w);
    float b1 = fmaf(-2.f, fmaf(q1.x, p1.x, fmaf(q1.y, p1.y, q1.z * p1.z)), p1.w);
    float b2 = fmaf(-2.f, fmaf(q1.x, p2.x, fmaf(q1.y, p2.y, q1.z * p2.z)), p2.w);
    float b3 = fmaf(-2.f, fmaf(q1.x, p3.x, fmaf(q1.y, p3.y, q1.z * p3.z)), p3.w);
    m1 = fminf(m1, fminf(fminf(b0, b1), fminf(b2, b3)));
  }

  float v = fmaxf(q0.w + m0, 0.f) + fmaxf(q1.w + m1, 0.f);

  // wave-64 shuffle reduction
  #pragma unroll
  for (int off = 32; off > 0; off >>= 1) {
    v += __shfl_down(v, off, 64);
  }
  if ((tid & 63) == 0) {
    atomicAdd(out, v * (1.0f / (float)BS));
  }
}

extern "C" void kernel_launch(void* const* d_in, const int* in_sizes, int n_in,
                              void* d_out, int out_size, void* d_ws, size_t ws_size,
                              hipStream_t stream) {
  const float* src_verts = (const float*)d_in[0];
  const float* dst_verts = (const float*)d_in[1];
  const int* src_idx = (const int*)d_in[2];
  const int* dst_idx = (const int*)d_in[3];
  float* out = (float*)d_out;

  float4* srcp = (float4*)d_ws;
  float4* dstp = srcp + BS;   // total 2 MB of workspace

  hipMemsetAsync(d_out, 0, sizeof(float), stream);

  chamfer_gather_kernel<<<(2 * BS + 255) / 256, 256, 0, stream>>>(
      src_verts, dst_verts, src_idx, dst_idx, srcp, dstp);

  chamfer_min_kernel<<<B * 2 * 8, 256, 0, stream>>>(srcp, dstp, out);
}

// Round 2
// 99.572 us; speedup vs baseline: 1.1219x; 1.1219x over previous
//
#include <hip/hip_runtime.h>
#include <hip/hip_bf16.h>
#include <math.h>

#define B 16
#define V 100000
#define S 4096
#define BS (B * S)   // 65536
#define NT 512       // threads per min-block (8 waves -> 2 waves/SIMD)

// ---------------------------------------------------------------------------
// Kernel 1: gather sampled points + precompute squared norm.
// Writes float4(x, y, z, x^2+y^2+z^2) per sampled point, SoA over [set][b*S+i].
// ---------------------------------------------------------------------------
__global__ __launch_bounds__(256) void chamfer_gather_kernel(
    const float* __restrict__ src_verts, const float* __restrict__ dst_verts,
    const int* __restrict__ src_idx, const int* __restrict__ dst_idx,
    float4* __restrict__ srcp, float4* __restrict__ dstp) {
  int t = blockIdx.x * 256 + threadIdx.x;
  if (t >= 2 * BS) return;
  int set = t >> 16;          // 0 = src, 1 = dst
  int i = t & (BS - 1);       // 0 .. B*S-1
  const float* verts = set ? dst_verts : src_verts;
  const int* idx = set ? dst_idx : src_idx;
  float4* op = set ? dstp : srcp;
  int b = i >> 12;            // i / S
  int v = idx[i];
  v = v < 0 ? 0 : (v >= V ? V - 1 : v);  // defensive clamp (no OOB faults)
  const float* p = verts + ((size_t)b * V + (size_t)v) * 3;
  float x = p[0], y = p[1], z = p[2];
  op[i] = make_float4(x, y, z, x * x + y * y + z * z);
}

// ---------------------------------------------------------------------------
// Kernel 2: per (batch, direction, chunk-of-512-queries) block, 512 threads.
// Stages all 4096 "other" points (float4 = 64 KB) in LDS; each thread owns
// ONE query q (prescaled q' = -2q) and computes
//   m = min_j fma(q'x,px, fma(q'y,py, fma(q'z,pz, pw)))   [= d2_j - 2*dot]
// over all 4096 points (8-point unroll, min3-friendly tree), then
// val = max(q.w + m, 0). Wave shuffle-sum -> one atomicAdd per wave.
// Grid = B * 2 * 8 = 256 blocks (1 per CU), 8 waves/CU = 2 waves/SIMD.
// ---------------------------------------------------------------------------
__global__ __launch_bounds__(NT) void chamfer_min_kernel(
    const float4* __restrict__ srcp, const float4* __restrict__ dstp,
    float* __restrict__ out) {
  __shared__ float4 pts[S];  // 64 KB

  int bid = blockIdx.x;
  int b = bid >> 4;          // /16
  int rem = bid & 15;
  int dir = rem >> 3;
  int chunk = rem & 7;

  const float4* qbase = dir == 0 ? srcp : dstp;
  const float4* obase = dir == 0 ? dstp : srcp;
  const float4* op = obase + (size_t)b * S;

  int tid = threadIdx.x;
  // cooperative, coalesced LDS fill: 4096 float4 / 512 threads = 8 each
  #pragma unroll
  for (int i = 0; i < S / NT; ++i) {
    pts[i * NT + tid] = op[i * NT + tid];
  }
  __syncthreads();

  float4 q = qbase[b * S + chunk * NT + tid];
  float qx = -2.f * q.x, qy = -2.f * q.y, qz = -2.f * q.z;

  float m = INFINITY;

  for (int j = 0; j < S; j += 8) {
    float4 p0 = pts[j + 0];
    float4 p1 = pts[j + 1];
    float4 p2 = pts[j + 2];
    float4 p3 = pts[j + 3];
    float4 p4 = pts[j + 4];
    float4 p5 = pts[j + 5];
    float4 p6 = pts[j + 6];
    float4 p7 = pts[j + 7];

    float a0 = fmaf(qx, p0.x, fmaf(qy, p0.y, fmaf(qz, p0.z, p0.w)));
    float a1 = fmaf(qx, p1.x, fmaf(qy, p1.y, fmaf(qz, p1.z, p1.w)));
    float a2 = fmaf(qx, p2.x, fmaf(qy, p2.y, fmaf(qz, p2.z, p2.w)));
    float a3 = fmaf(qx, p3.x, fmaf(qy, p3.y, fmaf(qz, p3.z, p3.w)));
    float a4 = fmaf(qx, p4.x, fmaf(qy, p4.y, fmaf(qz, p4.z, p4.w)));
    float a5 = fmaf(qx, p5.x, fmaf(qy, p5.y, fmaf(qz, p5.z, p5.w)));
    float a6 = fmaf(qx, p6.x, fmaf(qy, p6.y, fmaf(qz, p6.z, p6.w)));
    float a7 = fmaf(qx, p7.x, fmaf(qy, p7.y, fmaf(qz, p7.z, p7.w)));

    // min3-friendly tree: fminf(fminf(a,b),c) -> v_min3_f32
    float t0 = fminf(fminf(a0, a1), a2);
    float t1 = fminf(fminf(a3, a4), a5);
    float t2 = fminf(fminf(a6, a7), m);
    m = fminf(fminf(t0, t1), t2);
  }

  float val = fmaxf(q.w + m, 0.f) * (1.0f / (float)BS);

  // wave-64 shuffle reduction
  #pragma unroll
  for (int off = 32; off > 0; off >>= 1) {
    val += __shfl_down(val, off, 64);
  }
  if ((tid & 63) == 0) {
    atomicAdd(out, val);
  }
}

extern "C" void kernel_launch(void* const* d_in, const int* in_sizes, int n_in,
                              void* d_out, int out_size, void* d_ws, size_t ws_size,
                              hipStream_t stream) {
  const float* src_verts = (const float*)d_in[0];
  const float* dst_verts = (const float*)d_in[1];
  const int* src_idx = (const int*)d_in[2];
  const int* dst_idx = (const int*)d_in[3];
  float* out = (float*)d_out;

  float4* srcp = (float4*)d_ws;
  float4* dstp = srcp + BS;   // total 2 MB of workspace

  hipMemsetAsync(d_out, 0, sizeof(float), stream);

  chamfer_gather_kernel<<<(2 * BS + 255) / 256, 256, 0, stream>>>(
      src_verts, dst_verts, src_idx, dst_idx, srcp, dstp);

  chamfer_min_kernel<<<B * 2 * 8, NT, 0, stream>>>(srcp, dstp, out);
}

// Round 3
// 87.769 us; speedup vs baseline: 1.2727x; 1.1345x over previous
//
#include <hip/hip_runtime.h>
#include <hip/hip_bf16.h>
#include <math.h>

#define B 16
#define V 100000
#define S 4096
#define BS (B * S)                  // 65536 samples per set
#define NPAIR (S / 2)               // 2048 point-pairs per (set, b)
#define PC 8                        // point chunks per (b, dir)
#define PAIRS_PER_BLK (S / PC / 2)  // 256 pairs -> lds[512] float4 = 8 KB
#define NT 512                      // threads per min-block (8 waves, 2/SIMD)
#define Q 8                         // queries per thread (NT * Q = S)

typedef float v2f __attribute__((ext_vector_type(2)));

// ws layout (float4 units):
//   plain[set][b*S + i]          : float4(x,y,z,|p|^2)          @ set*BS
//   packed[set][(b*NPAIR+j)*2+k] : {x0,x1,y0,y1} / {z0,z1,w0,w1} @ 2*BS + set*BS
//   partials (float)             : [pair(32)][pc(8)][q(4096)]    @ byte 4*BS*16
// total = 8 MB

// ---------------------------------------------------------------------------
// Kernel 1: gather; one thread per point-PAIR per set. Writes both the plain
// query layout and the packed pair-SoA layout for pk_fma consumption.
// ---------------------------------------------------------------------------
__global__ __launch_bounds__(256) void chamfer_gather_kernel(
    const float* __restrict__ src_verts, const float* __restrict__ dst_verts,
    const int* __restrict__ src_idx, const int* __restrict__ dst_idx,
    float4* __restrict__ ws4) {
  int t = blockIdx.x * 256 + threadIdx.x;  // 0 .. 2*BS/2-1 = 65535
  int set = t >> 15;                       // 32768 pair-threads per set
  int r = t & 32767;                       // b*NPAIR + j
  const float* verts = set ? dst_verts : src_verts;
  const int* idx = set ? dst_idx : src_idx;
  int b = r >> 11;                         // / NPAIR
  int i0 = 2 * r;                          // global sample idx b*S + 2j
  int i1 = i0 + 1;

  int v0 = idx[i0], v1 = idx[i1];
  v0 = v0 < 0 ? 0 : (v0 >= V ? V - 1 : v0);
  v1 = v1 < 0 ? 0 : (v1 >= V ? V - 1 : v1);
  const float* p0 = verts + ((size_t)b * V + (size_t)v0) * 3;
  const float* p1 = verts + ((size_t)b * V + (size_t)v1) * 3;
  float x0 = p0[0], y0 = p0[1], z0 = p0[2];
  float x1 = p1[0], y1 = p1[1], z1 = p1[2];
  float w0 = x0 * x0 + y0 * y0 + z0 * z0;
  float w1 = x1 * x1 + y1 * y1 + z1 * z1;

  float4* plain = ws4 + (size_t)set * BS;
  plain[i0] = make_float4(x0, y0, z0, w0);
  plain[i1] = make_float4(x1, y1, z1, w1);

  float4* pk = ws4 + 2 * BS + (size_t)set * BS;
  pk[2 * r + 0] = make_float4(x0, x1, y0, y1);
  pk[2 * r + 1] = make_float4(z0, z1, w0, w1);
}

// ---------------------------------------------------------------------------
// Kernel 2: block = (b, dir, point-chunk pc). All 4096 queries of the pair
// live in registers (Q=8 per thread, prescaled by -2); the 512-point chunk is
// staged packed in 8 KB LDS. Inner body per point-pair per query:
//   3 x v_pk_fma_f32 + 1 x v_min3_f32  (2 VALU per eval)
// Writes per-query partial mins; combined in kernel 3.
// ---------------------------------------------------------------------------
__global__ __launch_bounds__(NT) void chamfer_min_kernel(
    const float4* __restrict__ ws4, float* __restrict__ partials) {
  __shared__ float4 lds[2 * PAIRS_PER_BLK];  // 512 float4 = 8 KB

  int bid = blockIdx.x;     // 0..255
  int pc = bid & (PC - 1);
  int pair = bid >> 3;      // 0..31 = b*2 + dir
  int b = pair >> 1;
  int dir = pair & 1;       // 0: q=src, o=dst ; 1: q=dst, o=src
  int qset = dir;
  int oset = 1 - dir;

  const float4* qplain = ws4 + (size_t)qset * BS + b * S;
  const float4* opk =
      ws4 + 2 * BS + (size_t)oset * BS + ((size_t)b * NPAIR + pc * PAIRS_PER_BLK) * 2;

  int tid = threadIdx.x;
  lds[tid] = opk[tid];      // 512 threads x 1 float4, coalesced
  __syncthreads();

  v2f qx[Q], qy[Q], qz[Q];
  float mn[Q];
  #pragma unroll
  for (int k = 0; k < Q; ++k) {
    float4 qq = qplain[tid + k * NT];
    float sx = -2.f * qq.x, sy = -2.f * qq.y, sz = -2.f * qq.z;
    qx[k] = (v2f){sx, sx};
    qy[k] = (v2f){sy, sy};
    qz[k] = (v2f){sz, sz};
    mn[k] = INFINITY;
  }

  #pragma unroll 4
  for (int j = 0; j < PAIRS_PER_BLK; ++j) {
    float4 A = lds[2 * j];      // {x0,x1,y0,y1}
    float4 Bp = lds[2 * j + 1]; // {z0,z1,w0,w1}
    v2f px = (v2f){A.x, A.y};
    v2f py = (v2f){A.z, A.w};
    v2f pz = (v2f){Bp.x, Bp.y};
    v2f pw = (v2f){Bp.z, Bp.w};
    #pragma unroll
    for (int k = 0; k < Q; ++k) {
      v2f a = __builtin_elementwise_fma(qz[k], pz, pw);
      a = __builtin_elementwise_fma(qy[k], py, a);
      a = __builtin_elementwise_fma(qx[k], px, a);
      mn[k] = fminf(fminf(a.x, a.y), mn[k]);  // v_min3_f32
    }
  }

  float* pp = partials + (size_t)(pair * PC + pc) * S;
  #pragma unroll
  for (int k = 0; k < Q; ++k) {
    pp[tid + k * NT] = mn[k];  // coalesced
  }
}

// ---------------------------------------------------------------------------
// Kernel 3: combine the PC partial mins per query, add |q|^2, clamp, mean.
// ---------------------------------------------------------------------------
__global__ __launch_bounds__(256) void chamfer_finish_kernel(
    const float4* __restrict__ ws4, const float* __restrict__ partials,
    float* __restrict__ out) {
  int t = blockIdx.x * 256 + threadIdx.x;  // 0 .. 2*BS-1
  int pair = t >> 12;
  int q = t & (S - 1);
  int b = pair >> 1;
  int dir = pair & 1;
  int qset = dir;

  const float* pp = partials + (size_t)pair * PC * S + q;
  float m = pp[0];
  #pragma unroll
  for (int pc = 1; pc < PC; ++pc) m = fminf(m, pp[(size_t)pc * S]);

  float qw = ws4[(size_t)qset * BS + b * S + q].w;
  float val = fmaxf(qw + m, 0.f) * (1.0f / (float)BS);

  #pragma unroll
  for (int off = 32; off > 0; off >>= 1) {
    val += __shfl_down(val, off, 64);
  }
  if ((threadIdx.x & 63) == 0) {
    atomicAdd(out, val);
  }
}

extern "C" void kernel_launch(void* const* d_in, const int* in_sizes, int n_in,
                              void* d_out, int out_size, void* d_ws, size_t ws_size,
                              hipStream_t stream) {
  const float* src_verts = (const float*)d_in[0];
  const float* dst_verts = (const float*)d_in[1];
  const int* src_idx = (const int*)d_in[2];
  const int* dst_idx = (const int*)d_in[3];
  float* out = (float*)d_out;

  float4* ws4 = (float4*)d_ws;                    // 4 MB: plain + packed
  float* partials = (float*)(ws4 + 4 * BS);       // 4 MB: 32*8*4096 floats

  hipMemsetAsync(d_out, 0, sizeof(float), stream);

  chamfer_gather_kernel<<<(2 * BS / 2) / 256, 256, 0, stream>>>(
      src_verts, dst_verts, src_idx, dst_idx, ws4);

  chamfer_min_kernel<<<B * 2 * PC, NT, 0, stream>>>(ws4, partials);

  chamfer_finish_kernel<<<2 * BS / 256, 256, 0, stream>>>(ws4, partials, out);
}

// Round 4
// 86.419 us; speedup vs baseline: 1.2926x; 1.0156x over previous
//
#include <hip/hip_runtime.h>
#include <hip/hip_bf16.h>
#include <math.h>

#define B 16
#define V 100000
#define S 4096
#define BS (B * S)                  // 65536 samples per set
#define NPAIR (S / 2)               // 2048 point-pairs per (set, b)
#define PC 16                       // point chunks per (b, dir)
#define PAIRS_PER_BLK (NPAIR / PC)  // 128 pairs -> lds[256] float4 = 4 KB
#define NT 256                      // threads per min-block (4 waves)
#define Q 16                        // queries per thread (NT * Q = S)

typedef float v2f __attribute__((ext_vector_type(2)));

// Forced packed-f32 FMA: d = a*b + c (elementwise, 2 lanes). The compiler
// scalarizes <2 x float> fma (R3 counters proved it), so emit VOP3P directly.
static __device__ __forceinline__ v2f pk_fma(v2f a, v2f b, v2f c) {
  v2f d;
  asm("v_pk_fma_f32 %0, %1, %2, %3" : "=v"(d) : "v"(a), "v"(b), "v"(c));
  return d;
}

// ws layout (float4 units):
//   plain[set][b*S + i]          : float4(x,y,z,|p|^2)           @ 0, 2 MB
//   packed[set][(b*NPAIR+j)*2+k] : {x0,x1,y0,y1}/{z0,z1,w0,w1}   @ 2*BS, 2 MB
//   partials (float)             : [pair(32)][pc(16)][q(4096)]    @ 4*BS, 8 MB
// total = 12 MB

// ---------------------------------------------------------------------------
// Kernel 1: gather; one thread per point-PAIR per set. Writes both the plain
// query layout and the packed pair-SoA layout.
// ---------------------------------------------------------------------------
__global__ __launch_bounds__(256) void chamfer_gather_kernel(
    const float* __restrict__ src_verts, const float* __restrict__ dst_verts,
    const int* __restrict__ src_idx, const int* __restrict__ dst_idx,
    float4* __restrict__ ws4) {
  int t = blockIdx.x * 256 + threadIdx.x;  // 0 .. 65535
  int set = t >> 15;                       // 32768 pair-threads per set
  int r = t & 32767;                       // b*NPAIR + j
  const float* verts = set ? dst_verts : src_verts;
  const int* idx = set ? dst_idx : src_idx;
  int b = r >> 11;                         // / NPAIR
  int i0 = 2 * r;                          // global sample idx b*S + 2j
  int i1 = i0 + 1;

  int v0 = idx[i0], v1 = idx[i1];
  v0 = v0 < 0 ? 0 : (v0 >= V ? V - 1 : v0);
  v1 = v1 < 0 ? 0 : (v1 >= V ? V - 1 : v1);
  const float* p0 = verts + ((size_t)b * V + (size_t)v0) * 3;
  const float* p1 = verts + ((size_t)b * V + (size_t)v1) * 3;
  float x0 = p0[0], y0 = p0[1], z0 = p0[2];
  float x1 = p1[0], y1 = p1[1], z1 = p1[2];
  float w0 = x0 * x0 + y0 * y0 + z0 * z0;
  float w1 = x1 * x1 + y1 * y1 + z1 * z1;

  float4* plain = ws4 + (size_t)set * BS;
  plain[i0] = make_float4(x0, y0, z0, w0);
  plain[i1] = make_float4(x1, y1, z1, w1);

  float4* pk = ws4 + 2 * BS + (size_t)set * BS;
  pk[2 * r + 0] = make_float4(x0, x1, y0, y1);
  pk[2 * r + 1] = make_float4(z0, z1, w0, w1);
}

// ---------------------------------------------------------------------------
// Kernel 2: block = (b, dir, point-chunk pc). ALL 4096 queries of (b,dir)
// live in registers (Q=16/thread, prescaled by -2, broadcast to v2f); the
// 256-point chunk is staged packed in 4 KB LDS. Inner body per point-pair
// per query: 3 x v_pk_fma_f32 (asm) + 1 x v_min3_f32 = 2 VALU per eval.
// Each ds_read_b128 pair feeds 16 queries = 32 evals.
// ---------------------------------------------------------------------------
__global__ __launch_bounds__(NT) void chamfer_min_kernel(
    const float4* __restrict__ ws4, float* __restrict__ partials) {
  __shared__ float4 lds[2 * PAIRS_PER_BLK];  // 256 float4 = 4 KB

  int bid = blockIdx.x;     // 0..511
  int pc = bid & (PC - 1);
  int pair = bid >> 4;      // 0..31 = b*2 + dir
  int b = pair >> 1;
  int dir = pair & 1;       // 0: q=src, o=dst ; 1: q=dst, o=src
  int qset = dir;
  int oset = 1 - dir;

  const float4* qplain = ws4 + (size_t)qset * BS + b * S;
  const float4* opk =
      ws4 + 2 * BS + (size_t)oset * BS + ((size_t)b * NPAIR + pc * PAIRS_PER_BLK) * 2;

  int tid = threadIdx.x;
  lds[tid] = opk[tid];      // 256 threads x 1 float4, coalesced
  __syncthreads();

  v2f qx[Q], qy[Q], qz[Q];
  float mn[Q];
  #pragma unroll
  for (int k = 0; k < Q; ++k) {
    float4 qq = qplain[tid + k * NT];
    float sx = -2.f * qq.x, sy = -2.f * qq.y, sz = -2.f * qq.z;
    qx[k] = (v2f){sx, sx};
    qy[k] = (v2f){sy, sy};
    qz[k] = (v2f){sz, sz};
    mn[k] = INFINITY;
  }

  #pragma unroll 2
  for (int j = 0; j < PAIRS_PER_BLK; ++j) {
    float4 A = lds[2 * j];      // {x0,x1,y0,y1}
    float4 Bp = lds[2 * j + 1]; // {z0,z1,w0,w1}
    v2f px = (v2f){A.x, A.y};
    v2f py = (v2f){A.z, A.w};
    v2f pz = (v2f){Bp.x, Bp.y};
    v2f pw = (v2f){Bp.z, Bp.w};
    #pragma unroll
    for (int k = 0; k < Q; ++k) {
      v2f a = pk_fma(qz[k], pz, pw);
      a = pk_fma(qy[k], py, a);
      a = pk_fma(qx[k], px, a);
      mn[k] = fminf(fminf(a.x, a.y), mn[k]);  // v_min3_f32
    }
  }

  float* pp = partials + (size_t)(pair * PC + pc) * S;
  #pragma unroll
  for (int k = 0; k < Q; ++k) {
    pp[tid + k * NT] = mn[k];  // coalesced
  }
}

// ---------------------------------------------------------------------------
// Kernel 3: combine the PC partial mins per query, add |q|^2, clamp, mean.
// ---------------------------------------------------------------------------
__global__ __launch_bounds__(256) void chamfer_finish_kernel(
    const float4* __restrict__ ws4, const float* __restrict__ partials,
    float* __restrict__ out) {
  int t = blockIdx.x * 256 + threadIdx.x;  // 0 .. 2*BS-1
  int pair = t >> 12;
  int q = t & (S - 1);
  int b = pair >> 1;
  int dir = pair & 1;
  int qset = dir;

  const float* pp = partials + (size_t)pair * PC * S + q;
  float m = pp[0];
  #pragma unroll
  for (int pc = 1; pc < PC; ++pc) m = fminf(m, pp[(size_t)pc * S]);

  float qw = ws4[(size_t)qset * BS + b * S + q].w;
  float val = fmaxf(qw + m, 0.f) * (1.0f / (float)BS);

  #pragma unroll
  for (int off = 32; off > 0; off >>= 1) {
    val += __shfl_down(val, off, 64);
  }
  if ((threadIdx.x & 63) == 0) {
    atomicAdd(out, val);
  }
}

extern "C" void kernel_launch(void* const* d_in, const int* in_sizes, int n_in,
                              void* d_out, int out_size, void* d_ws, size_t ws_size,
                              hipStream_t stream) {
  const float* src_verts = (const float*)d_in[0];
  const float* dst_verts = (const float*)d_in[1];
  const int* src_idx = (const int*)d_in[2];
  const int* dst_idx = (const int*)d_in[3];
  float* out = (float*)d_out;

  float4* ws4 = (float4*)d_ws;                 // 4 MB: plain + packed
  float* partials = (float*)(ws4 + 4 * BS);    // 8 MB: 32*16*4096 floats

  hipMemsetAsync(d_out, 0, sizeof(float), stream);

  chamfer_gather_kernel<<<(2 * BS / 2) / 256, 256, 0, stream>>>(
      src_verts, dst_verts, src_idx, dst_idx, ws4);

  chamfer_min_kernel<<<B * 2 * PC, NT, 0, stream>>>(ws4, partials);

  chamfer_finish_kernel<<<2 * BS / 256, 256, 0, stream>>>(ws4, partials, out);
}

// Round 5
// 67.475 us; speedup vs baseline: 1.6555x; 1.2807x over previous
//
#include <hip/hip_runtime.h>
#include <hip/hip_bf16.h>
#include <math.h>

#define B 16
#define V 100000
#define S 4096
#define BS (B * S)      // 65536
#define NT 512
#define ONE_BF 0x3F80u  // 1.0 in bf16

typedef __attribute__((ext_vector_type(8))) short bf16x8;
typedef __attribute__((ext_vector_type(16))) float f32x16;

static __device__ __forceinline__ unsigned bft(float x) {
  return __float_as_uint(x) >> 16;  // truncating f32 -> bf16 bits
}
static __device__ __forceinline__ float bff(unsigned hbits) {
  return __uint_as_float(hbits << 16);
}
static __device__ __forceinline__ unsigned pk(unsigned lo, unsigned hi) {
  return (lo & 0xFFFFu) | (hi << 16);
}
// Swizzled 16B-chunk index within a 32-point tile (64 chunks):
// breaks the 8-way bank-quad conflict of stride-32B ds_read_b128 down to 4-way.
static __device__ __forceinline__ int swz(int c, int h) {
  int a = c >> 2;
  return 8 * a + ((((c & 3) << 1) + h) ^ a);
}

// ---------------------------------------------------------------------------
// Fused kernel: block = (b, jpanel of 512 dst rows, i-quarter of 1024 src).
// Stages gathered+split src K16-fragments in LDS; each of 8 waves owns two
// 32-row dst j-tiles (A-frags gathered in-registers, fixed for the loop).
// One mfma_f32_32x32x16_bf16 per (j-tile, i-tile) yields 1024 FULL distances
// (s2 + d2 - 2*dot, error-compensated bf16 hi/lo split, error ~1e-4).
// K-channel plan (A = dst side, B = src side), m=-2*h(d), n=-2*l(d):
//   k0-2:  m_c   * h_c(s)   k3-5: m_c * l_c(s)   k6-8: n_c * h_c(s)
//   k9-10: 1 * s2{h,l}      k11-12: d2{h,l} * 1  k13-15: 0
// Epilogue: per-reg running min (dst dir) + per-tile col tree-min -> LDS
// atomicMin (src dir). Mins clamped >=0 then compared as raw IEEE uints.
// ---------------------------------------------------------------------------
__global__ __launch_bounds__(NT, 4) void chamfer_mfma_kernel(
    const float* __restrict__ src_verts, const float* __restrict__ dst_verts,
    const int* __restrict__ src_idx, const int* __restrict__ dst_idx,
    unsigned* __restrict__ gmin /* [2*BS]: src mins, then dst mins */) {
  __shared__ uint4 sfrag[2048];    // 32 KB: 32 tiles x 64 swizzled 16B chunks
  __shared__ unsigned smin[1024];  // 4 KB: src partial mins (uint keys)

  int bid = blockIdx.x;
  int b = bid >> 5;
  int jp = (bid >> 2) & 7;
  int iq = bid & 3;
  int tid = threadIdx.x;

  // ---- stage this quarter's 1024 src points into LDS (gather + split + pack)
  for (int p = tid; p < 1024; p += NT) {
    int gi = b * S + iq * 1024 + p;
    int v = src_idx[gi];
    v = v < 0 ? 0 : (v >= V ? V - 1 : v);
    const float* pv = src_verts + ((size_t)b * V + v) * 3;
    float x = pv[0], y = pv[1], z = pv[2];
    unsigned hx = bft(x), hy = bft(y), hz = bft(z);
    unsigned lx = bft(x - bff(hx)), ly = bft(y - bff(hy)), lz = bft(z - bff(hz));
    float s2 = x * x + y * y + z * z;
    unsigned s2h = bft(s2);
    unsigned s2l = bft(s2 - bff(s2h));
    uint4 h0, h1;
    h0.x = pk(hx, hy);  h0.y = pk(hz, lx);      h0.z = pk(ly, lz);     h0.w = pk(hx, hy);
    h1.x = pk(hz, s2h); h1.y = pk(s2l, ONE_BF); h1.z = pk(ONE_BF, 0u); h1.w = 0u;
    int t = p >> 5, c = p & 31;
    sfrag[t * 64 + swz(c, 0)] = h0;
    sfrag[t * 64 + swz(c, 1)] = h1;
    smin[p] = 0xFFFFFFFFu;
  }

  // ---- A-fragments: each lane gathers its two dst rows (fixed all loop)
  int w = tid >> 6;
  int lane = tid & 63;
  int c = lane & 31, h = lane >> 5;

  bf16x8 A[2];
  #pragma unroll
  for (int t2 = 0; t2 < 2; ++t2) {
    int gj = b * S + jp * 512 + w * 64 + t2 * 32 + c;
    int v = dst_idx[gj];
    v = v < 0 ? 0 : (v >= V ? V - 1 : v);
    const float* pv = dst_verts + ((size_t)b * V + v) * 3;
    float x = pv[0], y = pv[1], z = pv[2];
    unsigned hx = bft(x), hy = bft(y), hz = bft(z);
    unsigned mx = bft(-2.f * bff(hx)), my = bft(-2.f * bff(hy)), mz = bft(-2.f * bff(hz));
    unsigned nx = bft(-2.f * (x - bff(hx)));
    unsigned ny = bft(-2.f * (y - bff(hy)));
    unsigned nz = bft(-2.f * (z - bff(hz)));
    float d2 = x * x + y * y + z * z;
    unsigned d2h = bft(d2);
    unsigned d2l = bft(d2 - bff(d2h));
    uint4 f;
    if (h == 0) {
      f.x = pk(mx, my); f.y = pk(mz, mx); f.z = pk(my, mz); f.w = pk(nx, ny);
    } else {
      f.x = pk(nz, ONE_BF); f.y = pk(ONE_BF, d2h); f.z = pk(d2l, 0u); f.w = 0u;
    }
    A[t2] = __builtin_bit_cast(bf16x8, f);
  }

  __syncthreads();

  f32x16 zero = {};
  f32x16 mn0, mn1;
  #pragma unroll
  for (int r = 0; r < 16; ++r) { mn0[r] = INFINITY; mn1[r] = INFINITY; }

  int raddr = swz(c, h);

  #pragma unroll 2
  for (int t = 0; t < 32; ++t) {
    uint4 bfu = sfrag[t * 64 + raddr];
    bf16x8 Bf = __builtin_bit_cast(bf16x8, bfu);
    f32x16 d0 = __builtin_amdgcn_mfma_f32_32x32x16_bf16(A[0], Bf, zero, 0, 0, 0);
    f32x16 d1 = __builtin_amdgcn_mfma_f32_32x32x16_bf16(A[1], Bf, zero, 0, 0, 0);
    #pragma unroll
    for (int r = 0; r < 16; ++r) mn0[r] = fminf(mn0[r], d0[r]);
    #pragma unroll
    for (int r = 0; r < 16; ++r) mn1[r] = fminf(mn1[r], d1[r]);
    // src-direction: fold this tile's 32 row-contributions for column c
    float t0 = fminf(fminf(d0[0], d0[1]), d0[2]);
    float t1 = fminf(fminf(d0[3], d0[4]), d0[5]);
    float t2 = fminf(fminf(d0[6], d0[7]), d0[8]);
    float t3 = fminf(fminf(d0[9], d0[10]), d0[11]);
    float t4 = fminf(fminf(d0[12], d0[13]), d0[14]);
    float t5 = fminf(fminf(d0[15], d1[0]), d1[1]);
    float t6 = fminf(fminf(d1[2], d1[3]), d1[4]);
    float t7 = fminf(fminf(d1[5], d1[6]), d1[7]);
    float t8 = fminf(fminf(d1[8], d1[9]), d1[10]);
    float t9 = fminf(fminf(d1[11], d1[12]), d1[13]);
    float ta = fminf(d1[14], d1[15]);
    float u0 = fminf(fminf(t0, t1), t2);
    float u1 = fminf(fminf(t3, t4), t5);
    float u2 = fminf(fminf(t6, t7), t8);
    float u3 = fminf(t9, ta);
    float m = fminf(fminf(u0, u1), fminf(u2, u3));
    float mv = fmaxf(m, 0.f);
    atomicMin(&smin[t * 32 + c], __float_as_uint(mv));
  }

  // ---- dst-direction flush: cross-lane min over the 32 columns, then global
  #pragma unroll
  for (int r = 0; r < 16; ++r) {
    float v0 = fmaxf(mn0[r], 0.f);
    float v1 = fmaxf(mn1[r], 0.f);
    #pragma unroll
    for (int off = 16; off >= 1; off >>= 1) {
      v0 = fminf(v0, __shfl_xor(v0, off, 64));
      v1 = fminf(v1, __shfl_xor(v1, off, 64));
    }
    if (c == 0) {
      int row = (r & 3) + 8 * (r >> 2) + 4 * h;  // verified 32x32 C/D layout
      int base = b * S + jp * 512 + w * 64 + row;
      atomicMin(&gmin[BS + base], __float_as_uint(v0));
      atomicMin(&gmin[BS + base + 32], __float_as_uint(v1));
    }
  }

  // ---- src-direction flush
  __syncthreads();
  for (int p = tid; p < 1024; p += NT) {
    atomicMin(&gmin[b * S + iq * 1024 + p], smin[p]);
  }
}

// ---------------------------------------------------------------------------
// Sum kernel: all 2*BS mins are clamped floats stored as raw uint keys.
// ---------------------------------------------------------------------------
__global__ __launch_bounds__(256) void chamfer_sum_kernel(
    const unsigned* __restrict__ gmin, float* __restrict__ out) {
  int t = blockIdx.x * 256 + threadIdx.x;  // grid 512 -> 131072 threads
  float v = __uint_as_float(gmin[t]) * (1.0f / (float)BS);
  #pragma unroll
  for (int off = 32; off > 0; off >>= 1) v += __shfl_down(v, off, 64);
  if ((threadIdx.x & 63) == 0) atomicAdd(out, v);
}

extern "C" void kernel_launch(void* const* d_in, const int* in_sizes, int n_in,
                              void* d_out, int out_size, void* d_ws, size_t ws_size,
                              hipStream_t stream) {
  const float* src_verts = (const float*)d_in[0];
  const float* dst_verts = (const float*)d_in[1];
  const int* src_idx = (const int*)d_in[2];
  const int* dst_idx = (const int*)d_in[3];
  float* out = (float*)d_out;

  unsigned* gmin = (unsigned*)d_ws;  // 512 KB

  hipMemsetAsync(d_out, 0, sizeof(float), stream);
  hipMemsetAsync(gmin, 0xFF, (size_t)2 * BS * sizeof(unsigned), stream);

  chamfer_mfma_kernel<<<16 * 8 * 4, NT, 0, stream>>>(
      src_verts, dst_verts, src_idx, dst_idx, gmin);

  chamfer_sum_kernel<<<2 * BS / 256, 256, 0, stream>>>(gmin, out);
}

// Round 6
// 64.766 us; speedup vs baseline: 1.7248x; 1.0418x over previous
//
#include <hip/hip_runtime.h>
#include <hip/hip_bf16.h>
#include <math.h>

#define B 16
#define V 100000
#define S 4096
#define BS (B * S)      // 65536
#define NT 512
#define ONE_BF 0x3F80u  // 1.0 in bf16

typedef __attribute__((ext_vector_type(8))) short bf16x8;
typedef __attribute__((ext_vector_type(16))) float f32x16;

static __device__ __forceinline__ unsigned bft(float x) {
  return __float_as_uint(x) >> 16;  // truncating f32 -> bf16 bits
}
static __device__ __forceinline__ float bff(unsigned hbits) {
  return __uint_as_float(hbits << 16);
}
static __device__ __forceinline__ unsigned pk(unsigned lo, unsigned hi) {
  return (lo & 0xFFFFu) | (hi << 16);
}
// Swizzled 16B-chunk index within a 32-point tile (64 chunks):
// breaks the 8-way bank-quad conflict of stride-32B ds_read_b128 down to 4-way.
static __device__ __forceinline__ int swz(int c, int h) {
  int a = c >> 2;
  return 8 * a + ((((c & 3) << 1) + h) ^ a);
}

// ---------------------------------------------------------------------------
// Init kernel: replaces hipMemsetAsync (rocclr fillBuffer took 41 us in-graph!).
// Seeds gmin[2*BS] with +INF-as-uint and zeroes the scalar output.
// 128 blocks x 256 threads x uint4 = 2*BS uints.
// ---------------------------------------------------------------------------
__global__ __launch_bounds__(256) void chamfer_init_kernel(
    uint4* __restrict__ gmin4, float* __restrict__ out) {
  int t = blockIdx.x * 256 + threadIdx.x;
  gmin4[t] = make_uint4(0xFFFFFFFFu, 0xFFFFFFFFu, 0xFFFFFFFFu, 0xFFFFFFFFu);
  if (t == 0) *out = 0.f;
}

// ---------------------------------------------------------------------------
// Fused kernel: block = (b, jpanel of 512 dst rows, i-quarter of 1024 src).
// Stages gathered+split src K16-fragments in LDS; each of 8 waves owns two
// 32-row dst j-tiles (A-frags gathered in-registers, fixed for the loop).
// One mfma_f32_32x32x16_bf16 per (j-tile, i-tile) yields 1024 FULL distances
// (s2 + d2 - 2*dot, error-compensated bf16 hi/lo split, error ~1e-4).
// K-channel plan (A = dst side, B = src side), m=-2*h(d), n=-2*l(d):
//   k0-2:  m_c   * h_c(s)   k3-5: m_c * l_c(s)   k6-8: n_c * h_c(s)
//   k9-10: 1 * s2{h,l}      k11-12: d2{h,l} * 1  k13-15: 0
// Epilogue: per-reg running min (dst dir) + per-tile col tree-min -> LDS
// atomicMin (src dir). Mins clamped >=0 then compared as raw IEEE uints.
// ---------------------------------------------------------------------------
__global__ __launch_bounds__(NT, 4) void chamfer_mfma_kernel(
    const float* __restrict__ src_verts, const float* __restrict__ dst_verts,
    const int* __restrict__ src_idx, const int* __restrict__ dst_idx,
    unsigned* __restrict__ gmin /* [2*BS]: src mins, then dst mins */) {
  __shared__ uint4 sfrag[2048];    // 32 KB: 32 tiles x 64 swizzled 16B chunks
  __shared__ unsigned smin[1024];  // 4 KB: src partial mins (uint keys)

  int bid = blockIdx.x;
  int b = bid >> 5;
  int jp = (bid >> 2) & 7;
  int iq = bid & 3;
  int tid = threadIdx.x;

  // ---- stage this quarter's 1024 src points into LDS (gather + split + pack)
  for (int p = tid; p < 1024; p += NT) {
    int gi = b * S + iq * 1024 + p;
    int v = src_idx[gi];
    v = v < 0 ? 0 : (v >= V ? V - 1 : v);
    const float* pv = src_verts + ((size_t)b * V + v) * 3;
    float x = pv[0], y = pv[1], z = pv[2];
    unsigned hx = bft(x), hy = bft(y), hz = bft(z);
    unsigned lx = bft(x - bff(hx)), ly = bft(y - bff(hy)), lz = bft(z - bff(hz));
    float s2 = x * x + y * y + z * z;
    unsigned s2h = bft(s2);
    unsigned s2l = bft(s2 - bff(s2h));
    uint4 h0, h1;
    h0.x = pk(hx, hy);  h0.y = pk(hz, lx);      h0.z = pk(ly, lz);     h0.w = pk(hx, hy);
    h1.x = pk(hz, s2h); h1.y = pk(s2l, ONE_BF); h1.z = pk(ONE_BF, 0u); h1.w = 0u;
    int t = p >> 5, c = p & 31;
    sfrag[t * 64 + swz(c, 0)] = h0;
    sfrag[t * 64 + swz(c, 1)] = h1;
    smin[p] = 0xFFFFFFFFu;
  }

  // ---- A-fragments: each lane gathers its two dst rows (fixed all loop)
  int w = tid >> 6;
  int lane = tid & 63;
  int c = lane & 31, h = lane >> 5;

  bf16x8 A[2];
  #pragma unroll
  for (int t2 = 0; t2 < 2; ++t2) {
    int gj = b * S + jp * 512 + w * 64 + t2 * 32 + c;
    int v = dst_idx[gj];
    v = v < 0 ? 0 : (v >= V ? V - 1 : v);
    const float* pv = dst_verts + ((size_t)b * V + v) * 3;
    float x = pv[0], y = pv[1], z = pv[2];
    unsigned hx = bft(x), hy = bft(y), hz = bft(z);
    unsigned mx = bft(-2.f * bff(hx)), my = bft(-2.f * bff(hy)), mz = bft(-2.f * bff(hz));
    unsigned nx = bft(-2.f * (x - bff(hx)));
    unsigned ny = bft(-2.f * (y - bff(hy)));
    unsigned nz = bft(-2.f * (z - bff(hz)));
    float d2 = x * x + y * y + z * z;
    unsigned d2h = bft(d2);
    unsigned d2l = bft(d2 - bff(d2h));
    uint4 f;
    if (h == 0) {
      f.x = pk(mx, my); f.y = pk(mz, mx); f.z = pk(my, mz); f.w = pk(nx, ny);
    } else {
      f.x = pk(nz, ONE_BF); f.y = pk(ONE_BF, d2h); f.z = pk(d2l, 0u); f.w = 0u;
    }
    A[t2] = __builtin_bit_cast(bf16x8, f);
  }

  __syncthreads();

  f32x16 zero = {};
  f32x16 mn0, mn1;
  #pragma unroll
  for (int r = 0; r < 16; ++r) { mn0[r] = INFINITY; mn1[r] = INFINITY; }

  int raddr = swz(c, h);

  #pragma unroll 2
  for (int t = 0; t < 32; ++t) {
    uint4 bfu = sfrag[t * 64 + raddr];
    bf16x8 Bf = __builtin_bit_cast(bf16x8, bfu);
    f32x16 d0 = __builtin_amdgcn_mfma_f32_32x32x16_bf16(A[0], Bf, zero, 0, 0, 0);
    f32x16 d1 = __builtin_amdgcn_mfma_f32_32x32x16_bf16(A[1], Bf, zero, 0, 0, 0);
    #pragma unroll
    for (int r = 0; r < 16; ++r) mn0[r] = fminf(mn0[r], d0[r]);
    #pragma unroll
    for (int r = 0; r < 16; ++r) mn1[r] = fminf(mn1[r], d1[r]);
    // src-direction: fold this tile's 32 row-contributions for column c
    float t0 = fminf(fminf(d0[0], d0[1]), d0[2]);
    float t1 = fminf(fminf(d0[3], d0[4]), d0[5]);
    float t2 = fminf(fminf(d0[6], d0[7]), d0[8]);
    float t3 = fminf(fminf(d0[9], d0[10]), d0[11]);
    float t4 = fminf(fminf(d0[12], d0[13]), d0[14]);
    float t5 = fminf(fminf(d0[15], d1[0]), d1[1]);
    float t6 = fminf(fminf(d1[2], d1[3]), d1[4]);
    float t7 = fminf(fminf(d1[5], d1[6]), d1[7]);
    float t8 = fminf(fminf(d1[8], d1[9]), d1[10]);
    float t9 = fminf(fminf(d1[11], d1[12]), d1[13]);
    float ta = fminf(d1[14], d1[15]);
    float u0 = fminf(fminf(t0, t1), t2);
    float u1 = fminf(fminf(t3, t4), t5);
    float u2 = fminf(fminf(t6, t7), t8);
    float u3 = fminf(t9, ta);
    float m = fminf(fminf(u0, u1), fminf(u2, u3));
    float mv = fmaxf(m, 0.f);
    atomicMin(&smin[t * 32 + c], __float_as_uint(mv));
  }

  // ---- dst-direction flush: cross-lane min over the 32 columns, then global
  #pragma unroll
  for (int r = 0; r < 16; ++r) {
    float v0 = fmaxf(mn0[r], 0.f);
    float v1 = fmaxf(mn1[r], 0.f);
    #pragma unroll
    for (int off = 16; off >= 1; off >>= 1) {
      v0 = fminf(v0, __shfl_xor(v0, off, 64));
      v1 = fminf(v1, __shfl_xor(v1, off, 64));
    }
    if (c == 0) {
      int row = (r & 3) + 8 * (r >> 2) + 4 * h;  // verified 32x32 C/D layout
      int base = b * S + jp * 512 + w * 64 + row;
      atomicMin(&gmin[BS + base], __float_as_uint(v0));
      atomicMin(&gmin[BS + base + 32], __float_as_uint(v1));
    }
  }

  // ---- src-direction flush
  __syncthreads();
  for (int p = tid; p < 1024; p += NT) {
    atomicMin(&gmin[b * S + iq * 1024 + p], smin[p]);
  }
}

// ---------------------------------------------------------------------------
// Sum kernel: all 2*BS mins are clamped floats stored as raw uint keys.
// ---------------------------------------------------------------------------
__global__ __launch_bounds__(256) void chamfer_sum_kernel(
    const unsigned* __restrict__ gmin, float* __restrict__ out) {
  int t = blockIdx.x * 256 + threadIdx.x;  // grid 512 -> 131072 threads
  float v = __uint_as_float(gmin[t]) * (1.0f / (float)BS);
  #pragma unroll
  for (int off = 32; off > 0; off >>= 1) v += __shfl_down(v, off, 64);
  if ((threadIdx.x & 63) == 0) atomicAdd(out, v);
}

extern "C" void kernel_launch(void* const* d_in, const int* in_sizes, int n_in,
                              void* d_out, int out_size, void* d_ws, size_t ws_size,
                              hipStream_t stream) {
  const float* src_verts = (const float*)d_in[0];
  const float* dst_verts = (const float*)d_in[1];
  const int* src_idx = (const int*)d_in[2];
  const int* dst_idx = (const int*)d_in[3];
  float* out = (float*)d_out;

  unsigned* gmin = (unsigned*)d_ws;  // 512 KB

  chamfer_init_kernel<<<2 * BS / 4 / 256, 256, 0, stream>>>((uint4*)gmin, out);

  chamfer_mfma_kernel<<<16 * 8 * 4, NT, 0, stream>>>(
      src_verts, dst_verts, src_idx, dst_idx, gmin);

  chamfer_sum_kernel<<<2 * BS / 256, 256, 0, stream>>>(gmin, out);
}

// Round 7
// 39.189 us; speedup vs baseline: 2.8505x; 1.6527x over previous
//
#include <hip/hip_runtime.h>
#include <hip/hip_bf16.h>
#include <math.h>

#define B 16
#define V 100000
#define S 4096
#define BS (B * S)      // 65536
#define NT 512
#define ONE_BF 0x3F80u  // 1.0 in bf16

typedef __attribute__((ext_vector_type(8))) short bf16x8;
typedef __attribute__((ext_vector_type(16))) float f32x16;

static __device__ __forceinline__ unsigned bft(float x) {
  return __float_as_uint(x) >> 16;  // truncating f32 -> bf16 bits
}
static __device__ __forceinline__ float bff(unsigned hbits) {
  return __uint_as_float(hbits << 16);
}
static __device__ __forceinline__ unsigned pk(unsigned lo, unsigned hi) {
  return (lo & 0xFFFFu) | (hi << 16);
}
// Swizzled 16B-chunk index within a 32-point tile (64 chunks):
// breaks the 8-way bank-quad conflict of stride-32B ds_read_b128 down to 4-way.
static __device__ __forceinline__ int swz(int c, int h) {
  int a = c >> 2;
  return 8 * a + ((((c & 3) << 1) + h) ^ a);
}

// ---------------------------------------------------------------------------
// Init kernel: seeds gmin[2*BS] with +INF-as-uint and zeroes the scalar out.
// ---------------------------------------------------------------------------
__global__ __launch_bounds__(256) void chamfer_init_kernel(
    uint4* __restrict__ gmin4, float* __restrict__ out) {
  int t = blockIdx.x * 256 + threadIdx.x;
  gmin4[t] = make_uint4(0xFFFFFFFFu, 0xFFFFFFFFu, 0xFFFFFFFFu, 0xFFFFFFFFu);
  if (t == 0) *out = 0.f;
}

// ---------------------------------------------------------------------------
// Fused kernel: block = (b, jpanel of 512 dst rows, i-quarter of 1024 src).
// Stages gathered+split src K16-fragments in LDS; each of 8 waves owns two
// 32-row dst j-tiles (A-frags gathered in-registers, fixed for the loop).
// One mfma_f32_32x32x16_bf16 per (j-tile, i-tile) yields 1024 FULL distances
// (s2 + d2 - 2*dot, error-compensated bf16 hi/lo split, error ~1e-4).
// Epilogue: per-reg running min (dst dir) + per-tile col tree-min -> LDS
// atomicMin (src dir). Mins clamped >=0 then compared as raw IEEE uints.
// ---------------------------------------------------------------------------
__global__ __launch_bounds__(NT, 4) void chamfer_mfma_kernel(
    const float* __restrict__ src_verts, const float* __restrict__ dst_verts,
    const int* __restrict__ src_idx, const int* __restrict__ dst_idx,
    unsigned* __restrict__ gmin /* [2*BS]: src mins, then dst mins */) {
  __shared__ uint4 sfrag[2048];    // 32 KB: 32 tiles x 64 swizzled 16B chunks
  __shared__ unsigned smin[1024];  // 4 KB: src partial mins (uint keys)

  int bid = blockIdx.x;
  int b = bid >> 5;
  int jp = (bid >> 2) & 7;
  int iq = bid & 3;
  int tid = threadIdx.x;

  // ---- stage this quarter's 1024 src points into LDS (gather + split + pack)
  for (int p = tid; p < 1024; p += NT) {
    int gi = b * S + iq * 1024 + p;
    int v = src_idx[gi];
    v = v < 0 ? 0 : (v >= V ? V - 1 : v);
    const float* pv = src_verts + ((size_t)b * V + v) * 3;
    float x = pv[0], y = pv[1], z = pv[2];
    unsigned hx = bft(x), hy = bft(y), hz = bft(z);
    unsigned lx = bft(x - bff(hx)), ly = bft(y - bff(hy)), lz = bft(z - bff(hz));
    float s2 = x * x + y * y + z * z;
    unsigned s2h = bft(s2);
    unsigned s2l = bft(s2 - bff(s2h));
    uint4 h0, h1;
    h0.x = pk(hx, hy);  h0.y = pk(hz, lx);      h0.z = pk(ly, lz);     h0.w = pk(hx, hy);
    h1.x = pk(hz, s2h); h1.y = pk(s2l, ONE_BF); h1.z = pk(ONE_BF, 0u); h1.w = 0u;
    int t = p >> 5, c = p & 31;
    sfrag[t * 64 + swz(c, 0)] = h0;
    sfrag[t * 64 + swz(c, 1)] = h1;
    smin[p] = 0xFFFFFFFFu;
  }

  // ---- A-fragments: each lane gathers its two dst rows (fixed all loop)
  int w = tid >> 6;
  int lane = tid & 63;
  int c = lane & 31, h = lane >> 5;

  bf16x8 A[2];
  #pragma unroll
  for (int t2 = 0; t2 < 2; ++t2) {
    int gj = b * S + jp * 512 + w * 64 + t2 * 32 + c;
    int v = dst_idx[gj];
    v = v < 0 ? 0 : (v >= V ? V - 1 : v);
    const float* pv = dst_verts + ((size_t)b * V + v) * 3;
    float x = pv[0], y = pv[1], z = pv[2];
    unsigned hx = bft(x), hy = bft(y), hz = bft(z);
    unsigned mx = bft(-2.f * bff(hx)), my = bft(-2.f * bff(hy)), mz = bft(-2.f * bff(hz));
    unsigned nx = bft(-2.f * (x - bff(hx)));
    unsigned ny = bft(-2.f * (y - bff(hy)));
    unsigned nz = bft(-2.f * (z - bff(hz)));
    float d2 = x * x + y * y + z * z;
    unsigned d2h = bft(d2);
    unsigned d2l = bft(d2 - bff(d2h));
    uint4 f;
    if (h == 0) {
      f.x = pk(mx, my); f.y = pk(mz, mx); f.z = pk(my, mz); f.w = pk(nx, ny);
    } else {
      f.x = pk(nz, ONE_BF); f.y = pk(ONE_BF, d2h); f.z = pk(d2l, 0u); f.w = 0u;
    }
    A[t2] = __builtin_bit_cast(bf16x8, f);
  }

  __syncthreads();

  f32x16 zero = {};
  f32x16 mn0, mn1;
  #pragma unroll
  for (int r = 0; r < 16; ++r) { mn0[r] = INFINITY; mn1[r] = INFINITY; }

  int raddr = swz(c, h);

  #pragma unroll 2
  for (int t = 0; t < 32; ++t) {
    uint4 bfu = sfrag[t * 64 + raddr];
    bf16x8 Bf = __builtin_bit_cast(bf16x8, bfu);
    f32x16 d0 = __builtin_amdgcn_mfma_f32_32x32x16_bf16(A[0], Bf, zero, 0, 0, 0);
    f32x16 d1 = __builtin_amdgcn_mfma_f32_32x32x16_bf16(A[1], Bf, zero, 0, 0, 0);
    #pragma unroll
    for (int r = 0; r < 16; ++r) mn0[r] = fminf(mn0[r], d0[r]);
    #pragma unroll
    for (int r = 0; r < 16; ++r) mn1[r] = fminf(mn1[r], d1[r]);
    // src-direction: fold this tile's 32 row-contributions for column c
    float t0 = fminf(fminf(d0[0], d0[1]), d0[2]);
    float t1 = fminf(fminf(d0[3], d0[4]), d0[5]);
    float t2 = fminf(fminf(d0[6], d0[7]), d0[8]);
    float t3 = fminf(fminf(d0[9], d0[10]), d0[11]);
    float t4 = fminf(fminf(d0[12], d0[13]), d0[14]);
    float t5 = fminf(fminf(d0[15], d1[0]), d1[1]);
    float t6 = fminf(fminf(d1[2], d1[3]), d1[4]);
    float t7 = fminf(fminf(d1[5], d1[6]), d1[7]);
    float t8 = fminf(fminf(d1[8], d1[9]), d1[10]);
    float t9 = fminf(fminf(d1[11], d1[12]), d1[13]);
    float ta = fminf(d1[14], d1[15]);
    float u0 = fminf(fminf(t0, t1), t2);
    float u1 = fminf(fminf(t3, t4), t5);
    float u2 = fminf(fminf(t6, t7), t8);
    float u3 = fminf(t9, ta);
    float m = fminf(fminf(u0, u1), fminf(u2, u3));
    float mv = fmaxf(m, 0.f);
    atomicMin(&smin[t * 32 + c], __float_as_uint(mv));
  }

  // ---- dst-direction flush: cross-lane min over the 32 columns, then global
  #pragma unroll
  for (int r = 0; r < 16; ++r) {
    float v0 = fmaxf(mn0[r], 0.f);
    float v1 = fmaxf(mn1[r], 0.f);
    #pragma unroll
    for (int off = 16; off >= 1; off >>= 1) {
      v0 = fminf(v0, __shfl_xor(v0, off, 64));
      v1 = fminf(v1, __shfl_xor(v1, off, 64));
    }
    if (c == 0) {
      int row = (r & 3) + 8 * (r >> 2) + 4 * h;  // verified 32x32 C/D layout
      int base = b * S + jp * 512 + w * 64 + row;
      atomicMin(&gmin[BS + base], __float_as_uint(v0));
      atomicMin(&gmin[BS + base + 32], __float_as_uint(v1));
    }
  }

  // ---- src-direction flush
  __syncthreads();
  for (int p = tid; p < 1024; p += NT) {
    atomicMin(&gmin[b * S + iq * 1024 + p], smin[p]);
  }
}

// ---------------------------------------------------------------------------
// Sum kernel: 64 blocks x 256 threads, grid-stride uint4 reads, per-block
// reduction, ONE atomicAdd per block (64 same-address atomics total, was 2048).
// ---------------------------------------------------------------------------
__global__ __launch_bounds__(256) void chamfer_sum_kernel(
    const uint4* __restrict__ gmin4, float* __restrict__ out) {
  __shared__ float red[4];
  int tid = threadIdx.x;
  int t = blockIdx.x * 256 + tid;  // 16384 threads, 32768 uint4 total
  float v = 0.f;
  #pragma unroll
  for (int k = 0; k < 2; ++k) {
    uint4 u = gmin4[t + k * 16384];
    v += __uint_as_float(u.x) + __uint_as_float(u.y) +
         __uint_as_float(u.z) + __uint_as_float(u.w);
  }
  v *= (1.0f / (float)BS);
  #pragma unroll
  for (int off = 32; off > 0; off >>= 1) v += __shfl_down(v, off, 64);
  if ((tid & 63) == 0) red[tid >> 6] = v;
  __syncthreads();
  if (tid == 0) {
    atomicAdd(out, (red[0] + red[1]) + (red[2] + red[3]));
  }
}

extern "C" void kernel_launch(void* const* d_in, const int* in_sizes, int n_in,
                              void* d_out, int out_size, void* d_ws, size_t ws_size,
                              hipStream_t stream) {
  const float* src_verts = (const float*)d_in[0];
  const float* dst_verts = (const float*)d_in[1];
  const int* src_idx = (const int*)d_in[2];
  const int* dst_idx = (const int*)d_in[3];
  float* out = (float*)d_out;

  unsigned* gmin = (unsigned*)d_ws;  // 512 KB

  chamfer_init_kernel<<<2 * BS / 4 / 256, 256, 0, stream>>>((uint4*)gmin, out);

  chamfer_mfma_kernel<<<16 * 8 * 4, NT, 0, stream>>>(
      src_verts, dst_verts, src_idx, dst_idx, gmin);

  chamfer_sum_kernel<<<64, 256, 0, stream>>>((const uint4*)gmin, out);
}

// Round 8
// 38.400 us; speedup vs baseline: 2.9091x; 1.0205x over previous
//
#include <hip/hip_runtime.h>
#include <hip/hip_bf16.h>
#include <math.h>

#define B 16
#define V 100000
#define S 4096
#define BS (B * S)      // 65536
#define NT 512
#define ONE_BF 0x3F80u  // 1.0 in bf16

typedef __attribute__((ext_vector_type(8))) short bf16x8;
typedef __attribute__((ext_vector_type(16))) float f32x16;

static __device__ __forceinline__ unsigned bft(float x) {
  return __float_as_uint(x) >> 16;  // truncating f32 -> bf16 bits
}
static __device__ __forceinline__ float bff(unsigned hbits) {
  return __uint_as_float(hbits << 16);
}
static __device__ __forceinline__ unsigned pk(unsigned lo, unsigned hi) {
  return (lo & 0xFFFFu) | (hi << 16);
}
// Swizzled 16B-chunk index within a 32-point tile (64 chunks):
// breaks the 8-way bank-quad conflict of stride-32B ds_read_b128 down to 4-way.
static __device__ __forceinline__ int swz(int c, int h) {
  int a = c >> 2;
  return 8 * a + ((((c & 3) << 1) + h) ^ a);
}

// ws layout (floats):
//   part_src[8][65536]  @ 0        (2 MB)  min over each jp panel, clamped
//   part_dst[4][65536]  @ 8*65536  (1 MB)  min over each iq quarter, clamped
//   bsum[64]            @ 12*65536
// All planes fully written by the mfma kernel -> NO init kernel needed.

// ---------------------------------------------------------------------------
// Fused kernel: block = (b, jpanel of 512 dst rows, i-quarter of 1024 src).
// Identical compute core to R7; flushes are now PLAIN STORES to disjoint
// per-(jp/iq) planes instead of 655K global atomicMins (+ h-premin halves
// the LDS atomicMin traffic). No global atomics anywhere.
// ---------------------------------------------------------------------------
__global__ __launch_bounds__(NT, 4) void chamfer_mfma_kernel(
    const float* __restrict__ src_verts, const float* __restrict__ dst_verts,
    const int* __restrict__ src_idx, const int* __restrict__ dst_idx,
    float* __restrict__ part_src, float* __restrict__ part_dst) {
  __shared__ uint4 sfrag[2048];    // 32 KB: 32 tiles x 64 swizzled 16B chunks
  __shared__ unsigned smin[1024];  // 4 KB: src partial mins (uint keys)

  int bid = blockIdx.x;
  int b = bid >> 5;
  int jp = (bid >> 2) & 7;
  int iq = bid & 3;
  int tid = threadIdx.x;

  // ---- stage this quarter's 1024 src points into LDS (gather + split + pack)
  for (int p = tid; p < 1024; p += NT) {
    int gi = b * S + iq * 1024 + p;
    int v = src_idx[gi];
    v = v < 0 ? 0 : (v >= V ? V - 1 : v);
    const float* pv = src_verts + ((size_t)b * V + v) * 3;
    float x = pv[0], y = pv[1], z = pv[2];
    unsigned hx = bft(x), hy = bft(y), hz = bft(z);
    unsigned lx = bft(x - bff(hx)), ly = bft(y - bff(hy)), lz = bft(z - bff(hz));
    float s2 = x * x + y * y + z * z;
    unsigned s2h = bft(s2);
    unsigned s2l = bft(s2 - bff(s2h));
    uint4 h0, h1;
    h0.x = pk(hx, hy);  h0.y = pk(hz, lx);      h0.z = pk(ly, lz);     h0.w = pk(hx, hy);
    h1.x = pk(hz, s2h); h1.y = pk(s2l, ONE_BF); h1.z = pk(ONE_BF, 0u); h1.w = 0u;
    int t = p >> 5, c = p & 31;
    sfrag[t * 64 + swz(c, 0)] = h0;
    sfrag[t * 64 + swz(c, 1)] = h1;
    smin[p] = 0xFFFFFFFFu;
  }

  // ---- A-fragments: each lane gathers its two dst rows (fixed all loop)
  int w = tid >> 6;
  int lane = tid & 63;
  int c = lane & 31, h = lane >> 5;

  bf16x8 A[2];
  #pragma unroll
  for (int t2 = 0; t2 < 2; ++t2) {
    int gj = b * S + jp * 512 + w * 64 + t2 * 32 + c;
    int v = dst_idx[gj];
    v = v < 0 ? 0 : (v >= V ? V - 1 : v);
    const float* pv = dst_verts + ((size_t)b * V + v) * 3;
    float x = pv[0], y = pv[1], z = pv[2];
    unsigned hx = bft(x), hy = bft(y), hz = bft(z);
    unsigned mx = bft(-2.f * bff(hx)), my = bft(-2.f * bff(hy)), mz = bft(-2.f * bff(hz));
    unsigned nx = bft(-2.f * (x - bff(hx)));
    unsigned ny = bft(-2.f * (y - bff(hy)));
    unsigned nz = bft(-2.f * (z - bff(hz)));
    float d2 = x * x + y * y + z * z;
    unsigned d2h = bft(d2);
    unsigned d2l = bft(d2 - bff(d2h));
    uint4 f;
    if (h == 0) {
      f.x = pk(mx, my); f.y = pk(mz, mx); f.z = pk(my, mz); f.w = pk(nx, ny);
    } else {
      f.x = pk(nz, ONE_BF); f.y = pk(ONE_BF, d2h); f.z = pk(d2l, 0u); f.w = 0u;
    }
    A[t2] = __builtin_bit_cast(bf16x8, f);
  }

  __syncthreads();

  f32x16 zero = {};
  f32x16 mn0, mn1;
  #pragma unroll
  for (int r = 0; r < 16; ++r) { mn0[r] = INFINITY; mn1[r] = INFINITY; }

  int raddr = swz(c, h);

  #pragma unroll 2
  for (int t = 0; t < 32; ++t) {
    uint4 bfu = sfrag[t * 64 + raddr];
    bf16x8 Bf = __builtin_bit_cast(bf16x8, bfu);
    f32x16 d0 = __builtin_amdgcn_mfma_f32_32x32x16_bf16(A[0], Bf, zero, 0, 0, 0);
    f32x16 d1 = __builtin_amdgcn_mfma_f32_32x32x16_bf16(A[1], Bf, zero, 0, 0, 0);
    #pragma unroll
    for (int r = 0; r < 16; ++r) mn0[r] = fminf(mn0[r], d0[r]);
    #pragma unroll
    for (int r = 0; r < 16; ++r) mn1[r] = fminf(mn1[r], d1[r]);
    // src-direction: fold this tile's 32 row-contributions for column c
    float t0 = fminf(fminf(d0[0], d0[1]), d0[2]);
    float t1 = fminf(fminf(d0[3], d0[4]), d0[5]);
    float t2 = fminf(fminf(d0[6], d0[7]), d0[8]);
    float t3 = fminf(fminf(d0[9], d0[10]), d0[11]);
    float t4 = fminf(fminf(d0[12], d0[13]), d0[14]);
    float t5 = fminf(fminf(d0[15], d1[0]), d1[1]);
    float t6 = fminf(fminf(d1[2], d1[3]), d1[4]);
    float t7 = fminf(fminf(d1[5], d1[6]), d1[7]);
    float t8 = fminf(fminf(d1[8], d1[9]), d1[10]);
    float t9 = fminf(fminf(d1[11], d1[12]), d1[13]);
    float ta = fminf(d1[14], d1[15]);
    float u0 = fminf(fminf(t0, t1), t2);
    float u1 = fminf(fminf(t3, t4), t5);
    float u2 = fminf(fminf(t6, t7), t8);
    float u3 = fminf(t9, ta);
    float m = fminf(fminf(u0, u1), fminf(u2, u3));
    float mv = fmaxf(m, 0.f);
    // pre-min across the two h-halves (same (t,c)), halve atomic traffic
    mv = fminf(mv, __shfl_xor(mv, 32, 64));
    if (h == 0) atomicMin(&smin[t * 32 + c], __float_as_uint(mv));
  }

  // ---- dst-direction flush: cross-lane min over the 32 columns, plain store
  #pragma unroll
  for (int r = 0; r < 16; ++r) {
    float v0 = fmaxf(mn0[r], 0.f);
    float v1 = fmaxf(mn1[r], 0.f);
    #pragma unroll
    for (int off = 16; off >= 1; off >>= 1) {
      v0 = fminf(v0, __shfl_xor(v0, off, 64));
      v1 = fminf(v1, __shfl_xor(v1, off, 64));
    }
    if (c == 0) {
      int row = (r & 3) + 8 * (r >> 2) + 4 * h;  // verified 32x32 C/D layout
      int gd = b * S + jp * 512 + w * 64 + row;
      part_dst[iq * BS + gd] = v0;
      part_dst[iq * BS + gd + 32] = v1;
    }
  }

  // ---- src-direction flush: plain coalesced store into this jp's plane
  __syncthreads();
  for (int p = tid; p < 1024; p += NT) {
    part_src[jp * BS + b * S + iq * 1024 + p] = __uint_as_float(smin[p]);
  }
}

// ---------------------------------------------------------------------------
// Reduce1: fold the 8 src planes and 4 dst planes (elementwise min), sum all
// points, one plain-store partial sum per block (64 blocks).
// ---------------------------------------------------------------------------
__global__ __launch_bounds__(256) void chamfer_reduce1_kernel(
    const float* __restrict__ parts, float* __restrict__ bsum) {
  __shared__ float red[4];
  int tid = threadIdx.x;
  int base = (blockIdx.x * 256 + tid) * 4;  // 16384 threads x 4 floats = BS

  const float4* ps = (const float4*)parts;            // src planes
  const float4* pd = (const float4*)(parts + 8 * BS); // dst planes
  int i4 = base >> 2;

  float4 ms = ps[i4];
  #pragma unroll
  for (int j = 1; j < 8; ++j) {
    float4 t = ps[j * (BS / 4) + i4];
    ms.x = fminf(ms.x, t.x); ms.y = fminf(ms.y, t.y);
    ms.z = fminf(ms.z, t.z); ms.w = fminf(ms.w, t.w);
  }
  float4 md = pd[i4];
  #pragma unroll
  for (int j = 1; j < 4; ++j) {
    float4 t = pd[j * (BS / 4) + i4];
    md.x = fminf(md.x, t.x); md.y = fminf(md.y, t.y);
    md.z = fminf(md.z, t.z); md.w = fminf(md.w, t.w);
  }
  float v = (ms.x + ms.y + ms.z + ms.w) + (md.x + md.y + md.z + md.w);
  v *= (1.0f / (float)BS);

  #pragma unroll
  for (int off = 32; off > 0; off >>= 1) v += __shfl_down(v, off, 64);
  if ((tid & 63) == 0) red[tid >> 6] = v;
  __syncthreads();
  if (tid == 0) bsum[blockIdx.x] = (red[0] + red[1]) + (red[2] + red[3]);
}

// ---------------------------------------------------------------------------
// Reduce2: 64 block sums -> scalar, plain store (no init, no atomics).
// ---------------------------------------------------------------------------
__global__ __launch_bounds__(64) void chamfer_reduce2_kernel(
    const float* __restrict__ bsum, float* __restrict__ out) {
  float v = bsum[threadIdx.x];
  #pragma unroll
  for (int off = 32; off > 0; off >>= 1) v += __shfl_down(v, off, 64);
  if (threadIdx.x == 0) *out = v;
}

extern "C" void kernel_launch(void* const* d_in, const int* in_sizes, int n_in,
                              void* d_out, int out_size, void* d_ws, size_t ws_size,
                              hipStream_t stream) {
  const float* src_verts = (const float*)d_in[0];
  const float* dst_verts = (const float*)d_in[1];
  const int* src_idx = (const int*)d_in[2];
  const int* dst_idx = (const int*)d_in[3];
  float* out = (float*)d_out;

  float* parts = (float*)d_ws;              // 12 planes x 256 KB = 3 MB
  float* part_src = parts;                  // [8][BS]
  float* part_dst = parts + 8 * BS;         // [4][BS]
  float* bsum = parts + 12 * BS;            // [64]

  chamfer_mfma_kernel<<<16 * 8 * 4, NT, 0, stream>>>(
      src_verts, dst_verts, src_idx, dst_idx, part_src, part_dst);

  chamfer_reduce1_kernel<<<64, 256, 0, stream>>>(parts, bsum);

  chamfer_reduce2_kernel<<<1, 64, 0, stream>>>(bsum, out);
}

// Round 9
// 38.276 us; speedup vs baseline: 2.9185x; 1.0032x over previous
//
#include <hip/hip_runtime.h>
#include <hip/hip_bf16.h>
#include <math.h>

#define B 16
#define V 100000
#define S 4096
#define BS (B * S)      // 65536
#define NT 512
#define JP 16           // dst panels of 256 rows
#define ONE_BF 0x3F80u  // 1.0 in bf16

typedef __attribute__((ext_vector_type(8))) short bf16x8;
typedef __attribute__((ext_vector_type(16))) float f32x16;

static __device__ __forceinline__ unsigned bft(float x) {
  return __float_as_uint(x) >> 16;  // truncating f32 -> bf16 bits
}
static __device__ __forceinline__ float bff(unsigned hbits) {
  return __uint_as_float(hbits << 16);
}
static __device__ __forceinline__ unsigned pk(unsigned lo, unsigned hi) {
  return (lo & 0xFFFFu) | (hi << 16);
}

// ws layout (floats):
//   part_src[16][BS] @ 0       (4 MB)  per-jp-panel src mins, clamped
//   part_dst[4][BS]  @ 16*BS   (1 MB)  per-iq-quarter dst mins, clamped
//   bsum[64]         @ 20*BS
// Every plane element is written -> no init kernel, no global atomics.

// ---------------------------------------------------------------------------
// Fused kernel: block = (b, jp of 256 dst rows, iq of 1024 src). 8 waves,
// ONE 32-row dst tile per wave (low VGPR: mn16 + d16 + A4 ~= 50 live regs,
// no spill risk under the 128 cap). Src fragments staged in LDS as dword-pair
// SoA: lane L reads bytes 8L..8L+7 per slot -> bank-balanced ds_read_b64 x2
// (R8's 16B-chunk layout was still 8-way conflicted; the old swz() only
// permuted which lanes collide, not the count).
// ---------------------------------------------------------------------------
__global__ __launch_bounds__(NT, 4) void chamfer_mfma_kernel(
    const float* __restrict__ src_verts, const float* __restrict__ dst_verts,
    const int* __restrict__ src_idx, const int* __restrict__ dst_idx,
    float* __restrict__ part_src, float* __restrict__ part_dst) {
  __shared__ uint2 sfrag[4096];    // 32 KB: 32 tiles x [slot2][lane64] uint2
  __shared__ unsigned smin[1024];  // 4 KB: src partial mins (clamped bits)

  int bid = blockIdx.x;
  int b = bid >> 6;
  int jp = (bid >> 2) & 15;
  int iq = bid & 3;
  int tid = threadIdx.x;

  // ---- stage this quarter's 1024 src points (gather + hi/lo split + pack)
  for (int p = tid; p < 1024; p += NT) {
    int gi = b * S + iq * 1024 + p;
    int v = src_idx[gi];
    v = v < 0 ? 0 : (v >= V ? V - 1 : v);
    const float* pv = src_verts + ((size_t)b * V + v) * 3;
    float x = pv[0], y = pv[1], z = pv[2];
    unsigned hx = bft(x), hy = bft(y), hz = bft(z);
    unsigned lx = bft(x - bff(hx)), ly = bft(y - bff(hy)), lz = bft(z - bff(hz));
    float s2 = x * x + y * y + z * z;
    unsigned s2h = bft(s2);
    unsigned s2l = bft(s2 - bff(s2h));
    int t = p >> 5, c = p & 31;
    // k0-7 fragment (h=0 lane c): [hx,hy, hz,lx, ly,lz, hx,hy]
    sfrag[t * 128 + c]       = make_uint2(pk(hx, hy), pk(hz, lx));
    sfrag[t * 128 + 64 + c]  = make_uint2(pk(ly, lz), pk(hx, hy));
    // k8-15 fragment (h=1 lane c): [hz,s2h, s2l,1, 1,0, 0,0]
    sfrag[t * 128 + 32 + c]      = make_uint2(pk(hz, s2h), pk(s2l, ONE_BF));
    sfrag[t * 128 + 96 + c]      = make_uint2(pk(ONE_BF, 0u), 0u);
    smin[p] = 0x7F800000u;  // +INF
  }

  // ---- A-fragment: each lane gathers its one dst row (fixed all loop)
  int w = tid >> 6;
  int lane = tid & 63;
  int c = lane & 31, h = lane >> 5;

  int gj = b * S + jp * 256 + w * 32 + c;
  int vd = dst_idx[gj];
  vd = vd < 0 ? 0 : (vd >= V ? V - 1 : vd);
  const float* pv = dst_verts + ((size_t)b * V + vd) * 3;
  float x = pv[0], y = pv[1], z = pv[2];
  unsigned hx = bft(x), hy = bft(y), hz = bft(z);
  unsigned mx = bft(-2.f * bff(hx)), my = bft(-2.f * bff(hy)), mz = bft(-2.f * bff(hz));
  unsigned nx = bft(-2.f * (x - bff(hx)));
  unsigned ny = bft(-2.f * (y - bff(hy)));
  unsigned nz = bft(-2.f * (z - bff(hz)));
  float d2 = x * x + y * y + z * z;
  unsigned d2h = bft(d2);
  unsigned d2l = bft(d2 - bff(d2h));
  uint4 fa;
  if (h == 0) {  // k0-7: [mx,my, mz,mx, my,mz, nx,ny]
    fa.x = pk(mx, my); fa.y = pk(mz, mx); fa.z = pk(my, mz); fa.w = pk(nx, ny);
  } else {       // k8-15: [nz,1, 1,d2h, d2l,0, 0,0]
    fa.x = pk(nz, ONE_BF); fa.y = pk(ONE_BF, d2h); fa.z = pk(d2l, 0u); fa.w = 0u;
  }
  bf16x8 A = __builtin_bit_cast(bf16x8, fa);

  __syncthreads();

  f32x16 zero = {};
  f32x16 mn;
  #pragma unroll
  for (int r = 0; r < 16; ++r) mn[r] = INFINITY;

  #pragma unroll 4
  for (int t = 0; t < 32; ++t) {
    uint2 u0 = sfrag[t * 128 + lane];        // dwords 0-1 of my fragment
    uint2 u1 = sfrag[t * 128 + 64 + lane];   // dwords 2-3
    bf16x8 Bf = __builtin_bit_cast(bf16x8, make_uint4(u0.x, u0.y, u1.x, u1.y));
    f32x16 d = __builtin_amdgcn_mfma_f32_32x32x16_bf16(A, Bf, zero, 0, 0, 0);
    // dst-direction running min (rows fixed per lane/reg)
    #pragma unroll
    for (int r = 0; r < 16; ++r) mn[r] = fminf(mn[r], d[r]);
    // src-direction: fold my 16 rows for column c of this tile
    float t0 = fminf(fminf(d[0], d[1]), d[2]);
    float t1 = fminf(fminf(d[3], d[4]), d[5]);
    float t2 = fminf(fminf(d[6], d[7]), d[8]);
    float t3 = fminf(fminf(d[9], d[10]), d[11]);
    float t4 = fminf(fminf(d[12], d[13]), d[14]);
    float m = fminf(fminf(fminf(t0, t1), fminf(t2, t3)), fminf(t4, d[15]));
    // both h halves hit the same address (2-way same-addr atomics are cheap)
    atomicMin(&smin[t * 32 + c], __float_as_uint(fmaxf(m, 0.f)));
  }

  // ---- dst-direction flush: min over 32 cols (xor 1..16 stays in h-half)
  #pragma unroll
  for (int r = 0; r < 16; ++r) {
    float v = mn[r];
    #pragma unroll
    for (int off = 16; off >= 1; off >>= 1) v = fminf(v, __shfl_xor(v, off, 64));
    if (c == 0) {
      int row = (r & 3) + 8 * (r >> 2) + 4 * h;  // verified 32x32 C/D layout
      part_dst[iq * BS + b * S + jp * 256 + w * 32 + row] = fmaxf(v, 0.f);
    }
  }

  // ---- src-direction flush: plain coalesced store into this jp's plane
  __syncthreads();
  for (int p = tid; p < 1024; p += NT) {
    part_src[jp * BS + b * S + iq * 1024 + p] = __uint_as_float(smin[p]);
  }
}

// ---------------------------------------------------------------------------
// Reduce1: fold 16 src planes + 4 dst planes (elementwise min), sum, one
// plain-store partial per block (64 blocks x 256 threads x float4 = BS).
// ---------------------------------------------------------------------------
__global__ __launch_bounds__(256) void chamfer_reduce1_kernel(
    const float* __restrict__ parts, float* __restrict__ bsum) {
  __shared__ float red[4];
  int tid = threadIdx.x;
  int i4 = blockIdx.x * 256 + tid;  // 16384 float4 slots = BS floats

  const float4* ps = (const float4*)parts;             // 16 src planes
  const float4* pd = (const float4*)(parts + 16 * BS); // 4 dst planes

  float4 ms = ps[i4];
  #pragma unroll
  for (int j = 1; j < 16; ++j) {
    float4 t = ps[j * (BS / 4) + i4];
    ms.x = fminf(ms.x, t.x); ms.y = fminf(ms.y, t.y);
    ms.z = fminf(ms.z, t.z); ms.w = fminf(ms.w, t.w);
  }
  float4 md = pd[i4];
  #pragma unroll
  for (int j = 1; j < 4; ++j) {
    float4 t = pd[j * (BS / 4) + i4];
    md.x = fminf(md.x, t.x); md.y = fminf(md.y, t.y);
    md.z = fminf(md.z, t.z); md.w = fminf(md.w, t.w);
  }
  float v = (ms.x + ms.y + ms.z + ms.w) + (md.x + md.y + md.z + md.w);
  v *= (1.0f / (float)BS);

  #pragma unroll
  for (int off = 32; off > 0; off >>= 1) v += __shfl_down(v, off, 64);
  if ((tid & 63) == 0) red[tid >> 6] = v;
  __syncthreads();
  if (tid == 0) bsum[blockIdx.x] = (red[0] + red[1]) + (red[2] + red[3]);
}

// ---------------------------------------------------------------------------
// Reduce2: 64 block sums -> scalar, plain store.
// ---------------------------------------------------------------------------
__global__ __launch_bounds__(64) void chamfer_reduce2_kernel(
    const float* __restrict__ bsum, float* __restrict__ out) {
  float v = bsum[threadIdx.x];
  #pragma unroll
  for (int off = 32; off > 0; off >>= 1) v += __shfl_down(v, off, 64);
  if (threadIdx.x == 0) *out = v;
}

extern "C" void kernel_launch(void* const* d_in, const int* in_sizes, int n_in,
                              void* d_out, int out_size, void* d_ws, size_t ws_size,
                              hipStream_t stream) {
  const float* src_verts = (const float*)d_in[0];
  const float* dst_verts = (const float*)d_in[1];
  const int* src_idx = (const int*)d_in[2];
  const int* dst_idx = (const int*)d_in[3];
  float* out = (float*)d_out;

  float* parts = (float*)d_ws;        // 20 planes x 256 KB = 5 MB
  float* part_src = parts;            // [16][BS]
  float* part_dst = parts + 16 * BS;  // [4][BS]
  float* bsum = parts + 20 * BS;      // [64]

  chamfer_mfma_kernel<<<B * JP * 4, NT, 0, stream>>>(
      src_verts, dst_verts, src_idx, dst_idx, part_src, part_dst);

  chamfer_reduce1_kernel<<<64, 256, 0, stream>>>(parts, bsum);

  chamfer_reduce2_kernel<<<1, 64, 0, stream>>>(bsum, out);
}

// Round 10
// 32.937 us; speedup vs baseline: 3.3915x; 1.1621x over previous
//
#include <hip/hip_runtime.h>
#include <hip/hip_bf16.h>
#include <math.h>

#define B 16
#define V 100000
#define S 4096
#define BS (B * S)      // 65536
#define NT 512
#define JP 16           // dst panels of 256 rows
#define ONE_BF 0x3F80u  // 1.0 in bf16

typedef __attribute__((ext_vector_type(8))) short bf16x8;
typedef __attribute__((ext_vector_type(16))) float f32x16;

static __device__ __forceinline__ unsigned bft(float x) {
  return __float_as_uint(x) >> 16;  // truncating f32 -> bf16 bits
}
static __device__ __forceinline__ float bff(unsigned hbits) {
  return __uint_as_float(hbits << 16);
}
static __device__ __forceinline__ unsigned pk(unsigned lo, unsigned hi) {
  return (lo & 0xFFFFu) | (hi << 16);
}

// ws layout (floats):
//   part_src[16][BS] @ 0       (4 MB)
//   part_dst[4][BS]  @ 16*BS   (1 MB)
//   bsum[64]         @ 20*BS
//   srcfrag          @ 21*BS   (2 MB)  B-side fragments, tile-swizzled
//   dstfrag          @ 29*BS   (2 MB)  A-side fragments, [point][h] uint4
// Every plane element is written -> no init kernel, no global atomics.

// ---------------------------------------------------------------------------
// Prep kernel: per-point fragment content computed ONCE (was recomputed by
// 16 (src) / 4 (dst) blocks via fully-divergent vertex gathers).
// src -> B-fragment dwords laid out EXACTLY as the mfma kernel's LDS wants
// them, so staging is a straight coalesced copy. dst -> A-fragment uint4x2.
// ---------------------------------------------------------------------------
__global__ __launch_bounds__(NT) void chamfer_prep_kernel(
    const float* __restrict__ src_verts, const float* __restrict__ dst_verts,
    const int* __restrict__ src_idx, const int* __restrict__ dst_idx,
    uint2* __restrict__ srcfrag, uint4* __restrict__ dstfrag) {
  int t = blockIdx.x * NT + threadIdx.x;  // 0 .. 2*BS-1 (set uniform per block)
  int set = t >> 16;
  int i = t & (BS - 1);  // b*S + p
  int b = i >> 12;

  const int* idx = set ? dst_idx : src_idx;
  const float* verts = set ? dst_verts : src_verts;
  int v = idx[i];
  v = v < 0 ? 0 : (v >= V ? V - 1 : v);
  const float* pv = verts + ((size_t)b * V + v) * 3;
  float x = pv[0], y = pv[1], z = pv[2];
  unsigned hx = bft(x), hy = bft(y), hz = bft(z);
  float n2 = x * x + y * y + z * z;
  unsigned n2h = bft(n2);
  unsigned n2l = bft(n2 - bff(n2h));

  if (set == 0) {
    // B-side (src): k0-7 = [hx,hy,hz,lx,ly,lz,hx,hy], k8-15 = [hz,s2h,s2l,1,1,0,0,0]
    unsigned lx = bft(x - bff(hx)), ly = bft(y - bff(hy)), lz = bft(z - bff(hz));
    int tile = i >> 5, c = i & 31;
    uint2* base = srcfrag + (size_t)tile * 128;  // 1024 B per tile
    base[c]      = make_uint2(pk(hx, hy), pk(hz, lx));   // h=0 dw 0-1
    base[64 + c] = make_uint2(pk(ly, lz), pk(hx, hy));   // h=0 dw 2-3
    base[32 + c] = make_uint2(pk(hz, n2h), pk(n2l, ONE_BF));  // h=1 dw 0-1
    base[96 + c] = make_uint2(pk(ONE_BF, 0u), 0u);            // h=1 dw 2-3
  } else {
    // A-side (dst): k0-7 = [mx,my,mz,mx,my,mz,nx,ny], k8-15 = [nz,1,1,d2h,d2l,0,0,0]
    unsigned mx = bft(-2.f * bff(hx)), my = bft(-2.f * bff(hy)), mz = bft(-2.f * bff(hz));
    unsigned nx = bft(-2.f * (x - bff(hx)));
    unsigned ny = bft(-2.f * (y - bff(hy)));
    unsigned nz = bft(-2.f * (z - bff(hz)));
    dstfrag[(size_t)i * 2]     = make_uint4(pk(mx, my), pk(mz, mx), pk(my, mz), pk(nx, ny));
    dstfrag[(size_t)i * 2 + 1] = make_uint4(pk(nz, ONE_BF), pk(ONE_BF, n2h), pk(n2l, 0u), 0u);
  }
}

// ---------------------------------------------------------------------------
// Fused kernel: block = (b, jp of 256 dst rows, iq of 1024 src). 8 waves,
// one 32-row dst tile per wave. Staging is now a coalesced 32 KB copy of
// pre-swizzled fragments (no gather, no float math). Epilogue uses an LDS
// transpose (stride-33) instead of 16x5 dependent shuffles per wave.
// ---------------------------------------------------------------------------
__global__ __launch_bounds__(NT, 4) void chamfer_mfma_kernel(
    const uint4* __restrict__ srcfrag4, const uint4* __restrict__ dstfrag,
    float* __restrict__ part_src, float* __restrict__ part_dst) {
  __shared__ struct {
    uint4 sfrag[2048];   // 32 KB: 32 tiles x 1024 B
    unsigned smin[1024]; // 4 KB
  } sh;
  // epilogue overlay: 256 rows x stride 33 floats = 33792 B (sfrag + smin[0:256])
  float* red = (float*)sh.sfrag;

  int bid = blockIdx.x;
  int b = bid >> 6;
  int jp = (bid >> 2) & 15;
  int iq = bid & 3;
  int tid = threadIdx.x;

  // ---- stage: straight coalesced copy of this quarter's fragment chunk
  const uint4* chunk = srcfrag4 + (size_t)(b * S + iq * 1024) * 2;  // 32 KB
  #pragma unroll
  for (int k = 0; k < 4; ++k) {
    sh.sfrag[tid + k * NT] = chunk[tid + k * NT];
  }
  for (int p = tid; p < 1024; p += NT) sh.smin[p] = 0x7F800000u;  // +INF

  // ---- A-fragment: coalesced-ish load of my dst row's half
  int w = tid >> 6;
  int lane = tid & 63;
  int c = lane & 31, h = lane >> 5;
  int gj = b * S + jp * 256 + w * 32 + c;
  bf16x8 A = __builtin_bit_cast(bf16x8, dstfrag[(size_t)gj * 2 + h]);

  __syncthreads();

  const uint2* sf2 = (const uint2*)sh.sfrag;
  f32x16 zero = {};
  f32x16 mn;
  #pragma unroll
  for (int r = 0; r < 16; ++r) mn[r] = INFINITY;

  #pragma unroll 4
  for (int t = 0; t < 32; ++t) {
    uint2 u0 = sf2[t * 128 + lane];
    uint2 u1 = sf2[t * 128 + 64 + lane];
    bf16x8 Bf = __builtin_bit_cast(bf16x8, make_uint4(u0.x, u0.y, u1.x, u1.y));
    f32x16 d = __builtin_amdgcn_mfma_f32_32x32x16_bf16(A, Bf, zero, 0, 0, 0);
    #pragma unroll
    for (int r = 0; r < 16; ++r) mn[r] = fminf(mn[r], d[r]);
    // src-direction: fold my 16 rows for column c of this tile
    float t0 = fminf(fminf(d[0], d[1]), d[2]);
    float t1 = fminf(fminf(d[3], d[4]), d[5]);
    float t2 = fminf(fminf(d[6], d[7]), d[8]);
    float t3 = fminf(fminf(d[9], d[10]), d[11]);
    float t4 = fminf(fminf(d[12], d[13]), d[14]);
    float m = fminf(fminf(fminf(t0, t1), fminf(t2, t3)), fminf(t4, d[15]));
    atomicMin(&sh.smin[t * 32 + c], __float_as_uint(fmaxf(m, 0.f)));
  }

  // ---- src-direction flush (before smin's tail byte gets reused by red)
  __syncthreads();
  for (int p = tid; p < 1024; p += NT) {
    part_src[jp * BS + b * S + iq * 1024 + p] = __uint_as_float(sh.smin[p]);
  }
  __syncthreads();

  // ---- dst-direction: LDS transpose, stride 33 (2-way-free banks both sides)
  #pragma unroll
  for (int r = 0; r < 16; ++r) {
    int row = w * 32 + (r & 3) + 8 * (r >> 2) + 4 * h;  // 32x32 C/D layout
    red[row * 33 + c] = mn[r];
  }
  __syncthreads();
  {
    int row = tid >> 1, half = tid & 1;
    const float* rp = red + row * 33 + half * 16;
    float a0 = fminf(fminf(rp[0], rp[1]), rp[2]);
    float a1 = fminf(fminf(rp[3], rp[4]), rp[5]);
    float a2 = fminf(fminf(rp[6], rp[7]), rp[8]);
    float a3 = fminf(fminf(rp[9], rp[10]), rp[11]);
    float a4 = fminf(fminf(rp[12], rp[13]), rp[14]);
    float m = fminf(fminf(fminf(a0, a1), fminf(a2, a3)), fminf(a4, rp[15]));
    m = fminf(m, __shfl_xor(m, 1, 64));
    if (half == 0) {
      part_dst[iq * BS + b * S + jp * 256 + row] = fmaxf(m, 0.f);
    }
  }
}

// ---------------------------------------------------------------------------
// Reduce1: fold 16 src planes + 4 dst planes (elementwise min), sum, one
// plain-store partial per block (64 blocks x 256 threads x float4 = BS).
// ---------------------------------------------------------------------------
__global__ __launch_bounds__(256) void chamfer_reduce1_kernel(
    const float* __restrict__ parts, float* __restrict__ bsum) {
  __shared__ float red[4];
  int tid = threadIdx.x;
  int i4 = blockIdx.x * 256 + tid;  // 16384 float4 slots = BS floats

  const float4* ps = (const float4*)parts;             // 16 src planes
  const float4* pd = (const float4*)(parts + 16 * BS); // 4 dst planes

  float4 ms = ps[i4];
  #pragma unroll
  for (int j = 1; j < 16; ++j) {
    float4 t = ps[j * (BS / 4) + i4];
    ms.x = fminf(ms.x, t.x); ms.y = fminf(ms.y, t.y);
    ms.z = fminf(ms.z, t.z); ms.w = fminf(ms.w, t.w);
  }
  float4 md = pd[i4];
  #pragma unroll
  for (int j = 1; j < 4; ++j) {
    float4 t = pd[j * (BS / 4) + i4];
    md.x = fminf(md.x, t.x); md.y = fminf(md.y, t.y);
    md.z = fminf(md.z, t.z); md.w = fminf(md.w, t.w);
  }
  float v = (ms.x + ms.y + ms.z + ms.w) + (md.x + md.y + md.z + md.w);
  v *= (1.0f / (float)BS);

  #pragma unroll
  for (int off = 32; off > 0; off >>= 1) v += __shfl_down(v, off, 64);
  if ((tid & 63) == 0) red[tid >> 6] = v;
  __syncthreads();
  if (tid == 0) bsum[blockIdx.x] = (red[0] + red[1]) + (red[2] + red[3]);
}

// ---------------------------------------------------------------------------
// Reduce2: 64 block sums -> scalar, plain store.
// ---------------------------------------------------------------------------
__global__ __launch_bounds__(64) void chamfer_reduce2_kernel(
    const float* __restrict__ bsum, float* __restrict__ out) {
  float v = bsum[threadIdx.x];
  #pragma unroll
  for (int off = 32; off > 0; off >>= 1) v += __shfl_down(v, off, 64);
  if (threadIdx.x == 0) *out = v;
}

extern "C" void kernel_launch(void* const* d_in, const int* in_sizes, int n_in,
                              void* d_out, int out_size, void* d_ws, size_t ws_size,
                              hipStream_t stream) {
  const float* src_verts = (const float*)d_in[0];
  const float* dst_verts = (const float*)d_in[1];
  const int* src_idx = (const int*)d_in[2];
  const int* dst_idx = (const int*)d_in[3];
  float* out = (float*)d_out;

  float* parts = (float*)d_ws;
  float* part_src = parts;                        // [16][BS]
  float* part_dst = parts + 16 * BS;              // [4][BS]
  float* bsum = parts + 20 * BS;                  // [64]
  uint2* srcfrag = (uint2*)(parts + 21 * BS);     // BS*4 uint2 (2 MB)
  uint4* dstfrag = (uint4*)(parts + 29 * BS);     // BS*2 uint4 (2 MB)

  chamfer_prep_kernel<<<2 * BS / NT, NT, 0, stream>>>(
      src_verts, dst_verts, src_idx, dst_idx, srcfrag, dstfrag);

  chamfer_mfma_kernel<<<B * JP * 4, NT, 0, stream>>>(
      (const uint4*)srcfrag, dstfrag, part_src, part_dst);

  chamfer_reduce1_kernel<<<64, 256, 0, stream>>>(parts, bsum);

  chamfer_reduce2_kernel<<<1, 64, 0, stream>>>(bsum, out);
}